// Round 7
// baseline (306.787 us; speedup 1.0000x reference)
//
#include <hip/hip_runtime.h>
#include <math.h>

#define A_DIM 60
#define NPATCH 625
#define SENT (1 << 20)

typedef short s16x8 __attribute__((ext_vector_type(8)));
typedef short s16x4 __attribute__((ext_vector_type(4)));
typedef float fx4   __attribute__((ext_vector_type(4)));

__device__ __forceinline__ short f2bf(float f) {
    unsigned u = __builtin_bit_cast(unsigned, f);
    unsigned r = (u + 0x7FFFu + ((u >> 16) & 1u)) >> 16;
    return (short)r;
}

// ---------------------------------------------------------------------------
// Prep (merged, cheap): blocks 0..624 -> window bases; 625..696 -> w2 A-pack;
// 697 -> w3 A-pack. (R5-verified)
// ---------------------------------------------------------------------------
__global__ __launch_bounds__(256) void k_prep(const int* __restrict__ masks,
                                              const float* __restrict__ w2,
                                              const float* __restrict__ w3,
                                              int* __restrict__ win,
                                              short* __restrict__ w2a,
                                              short* __restrict__ w3a)
{
    const int blk = blockIdx.x, tid = threadIdx.x;
    if (blk < NPATCH) {
        __shared__ int s_f[60][4];
        __shared__ int s_row[64];
        int r = tid >> 2, q = tid & 3;
        if (r < 60) {
            const int4* m4 = (const int4*)(masks + (blk * 60 + r) * 128 + q * 32);
            int first = SENT;
#pragma unroll
            for (int j = 0; j < 8; ++j) {
                int4 v = m4[j];
                int base = q * 32 + j * 4;
                if (v.w) first = min(first, base + 3);
                if (v.z) first = min(first, base + 2);
                if (v.y) first = min(first, base + 1);
                if (v.x) first = min(first, base);
            }
            s_f[r][q] = first;
        }
        __syncthreads();
        if (tid < 60)
            s_row[tid] = min(min(s_f[tid][0], s_f[tid][1]),
                             min(s_f[tid][2], s_f[tid][3]));
        __syncthreads();
        if (tid < 60) {
            int lo = SENT;
            for (int d = -3; d <= 3; ++d) {
                int rr = tid + d;
                if (rr >= 0 && rr < 60) lo = min(lo, s_row[rr]);
            }
            int b;
            if (lo >= SENT) b = SENT;
            else { b = lo - 3; if (b < 0) b = 0; if (b > 96) b = 96; }
            win[blk * 64 + tid] = b;
        }
    } else if (blk < 697) {
        int i = (blk - NPATCH) * 256 + tid;     // < 18432
        int ic = i & 31, ol = (i >> 5) & 15, b2i = i >> 9;
        int ks = b2i % 9, T = b2i / 9;
        int oc = T * 16 + ol, dy = ks / 3, dxx = ks % 3;
        w2a[i] = f2bf(w2[((oc * 32 + ic) * 3 + dy) * 3 + dxx]);
    } else {
#pragma unroll
        for (int jj = 0; jj < 4; ++jj) {
            int i = jj * 256 + tid;             // < 1024
            int k = i & 31, m = (i >> 5) & 15, s = i >> 9;
            int dy = m / 3, dxx = m % 3;
            float v = (m < 9) ? w3[((s * 32 + k) * 3 + dy) * 3 + dxx] : 0.f;
            w3a[i] = f2bf(v);
        }
    }
}

// ---------------------------------------------------------------------------
// Main pipeline: 2 blocks/patch, pair of rows per iter, 4 barriers/iter.
// Single s_x2 pair buffer (tap-GEMM moved to Seg B) -> 30.4 KB LDS ->
// 5 blocks/CU -> all 1250 blocks co-resident.
// Seg A: s_in write (prefetched) + next prefetch + LINEAR(f-5) + linw prefetch
// Seg B: CONV1 (pair f-1) + conv3 tap-GEMM (pair f-3, s_x2 from prev Seg C)
// Seg C: CONV2 MFMA (pair f-2) -> s_x2
// Seg D: COMBINE (pair f-4) -> s_out3[f&1]
// ---------------------------------------------------------------------------
__device__ __forceinline__ float lds_self(const float* rowp, int idx,
                                          const float* zp)
{
    const float* q = ((unsigned)idx < 32u) ? (rowp + idx) : zp;
    return *q;
}

__global__ __launch_bounds__(256, 5) void k_pipeline(
    const float* __restrict__ sino,
    const float* __restrict__ w1, const float* __restrict__ b1,
    const short* __restrict__ w2a, const float* __restrict__ b2w,
    const short* __restrict__ w3a, const float* __restrict__ b3,
    const float* __restrict__ linw,
    const int* __restrict__ masks, const int* __restrict__ win,
    float* __restrict__ patches)
{
    __shared__ float s_in[5][33];
    __shared__ __align__(16) short s_x1[5][32 * 40];   // ring 5: [col][32ic+pad]
    __shared__ __align__(16) short s_x2[2][32 * 72];   // single pair buffer
    __shared__ float s_D[5][9][34];                    // conv3 tap ring
    __shared__ float s_out3[2][2][32];                 // dbl-buffer pairs
    __shared__ float s_lin[200];
    __shared__ int   s_base[64];
    __shared__ __align__(16) short s_z32[16];          // 32B zeros

    const int tid = threadIdx.x;
    const int pb  = blockIdx.x;
    const int p   = pb >> 1;
    const int half = pb & 1;

    const int S     = half ? 27 : 0;
    const int in_hi = half ? 59 : 32;
    const int x1lo  = half ? 28 : 0,  x1hi = half ? 59 : 31;
    const int x2lo  = half ? 29 : 0,  x2hi = half ? 59 : 30;
    const int olo   = half ? 30 : 0,  ohi  = half ? 59 : 29;
    const int F     = half ? 22 : 20;

    // early-exit for fully-empty patches (also first barrier)
    int pred = (tid < 60) ? ((win[p * 64 + tid] < 128) ? 1 : 0) : 0;
    if (__syncthreads_count(pred) == 0) {
        if (tid < 25) patches[pb * 25 + tid] = 0.f;
        return;
    }

    if (tid < 64)
        s_base[tid] = (tid >= 2 && tid < 62) ? win[p * 64 + (tid - 2)] : SENT;
    if (tid < 16) s_z32[tid] = 0;

    const int lane   = tid & 63;
    const int n      = lane & 15;
    const int quad   = lane >> 4;
    const int col    = tid & 31;
    const int rowsub = (tid >> 5) & 1;
    const int grp    = __builtin_amdgcn_readfirstlane(tid >> 6);  // 0..3
    const float* zp  = (const float*)&s_z32[0];
    const short* z16 = &s_z32[0];

    // hoisted invariants
    s16x8 afrag2[9];
#pragma unroll
    for (int ks = 0; ks < 9; ++ks)
        afrag2[ks] = *(const s16x8*)(w2a + (grp * 9 + ks) * 512 + (n << 5) + (quad << 3));
    const s16x8 w3f0 = *(const s16x8*)(w3a + (n << 5) + (quad << 3));
    const s16x8 w3f1 = *(const s16x8*)(w3a + ((16 + n) << 5) + (quad << 3));
    const float4 bv = *(const float4*)(b2w + (grp << 4) + (quad << 2));
    fx4 binit; binit[0] = bv.x; binit[1] = bv.y; binit[2] = bv.z; binit[3] = bv.w;
    const float b3s = b3[0];

    const int lk = tid >> 3;
    const int lg = tid & 7;
    float lacc = 0.f;
    float pwv[2][4] = {{0.f,0.f,0.f,0.f},{0.f,0.f,0.f,0.f}};
    float pv = 0.f; int pm = 0;

    __syncthreads();

    // pre-loop input prefetch (pair 0)
    if (tid < 64) {
        int r = S + (tid >> 5);
        int b = s_base[r + 2];
        if (r <= in_hi && b < 128) {
            int t = b + col;
            pm = masks[(p * A_DIM + r) * 128 + t];
            pv = sino[r * 128 + t];
        }
    }

    for (int f = 0; f < F; ++f) {
        // ================= Seg A =================
        if (tid < 64) {
            int r = S + 2 * f + (tid >> 5);
            int b = s_base[r + 2];
            if (r <= in_hi && b < 128)
                s_in[r % 5][col] = pm ? pv : 0.f;
            int r2 = r + 2;                       // prefetch pair f+1
            int b2i = s_base[r2 + 2];
            if (r2 <= in_hi && b2i < 128) {
                int t = b2i + col;
                pm = masks[(p * A_DIM + r2) * 128 + t];
                pv = sino[r2 * 128 + t];
            }
        }
        {
            int q = f - 5;                        // LINEAR on pair f-5
            if (q >= 0 && tid < 200) {
#pragma unroll
                for (int rs = 0; rs < 2; ++rs) {
                    int r = S + 2 * q + rs;
                    if (r >= olo && r <= ohi) {
                        int b = s_base[r + 2];
                        if (b < 128) {
                            float a = lacc;
#pragma unroll
                            for (int i = 0; i < 4; ++i)
                                a = fmaf(s_out3[(f + 1) & 1][rs][lg + 8 * i],
                                         pwv[rs][i], a);
                            lacc = a;
                        }
                    }
                }
            }
            int q2 = f - 4;                       // linw prefetch for pair f-4
            if (q2 >= 0 && tid < 200) {
#pragma unroll
                for (int rs = 0; rs < 2; ++rs) {
                    int r = S + 2 * q2 + rs;
                    if (r >= olo && r <= ohi) {
                        int b = s_base[r + 2];
                        if (b < 128) {
                            const float* lwp = linw + lk * (A_DIM * 128) + r * 128 + b;
#pragma unroll
                            for (int i = 0; i < 4; ++i)
                                pwv[rs][i] = lwp[lg + 8 * i];
                        }
                    }
                }
            }
        }
        __syncthreads();

        // ========= Seg B: CONV1 (pair f-1) + conv3 tap (pair f-3) =========
        {
            int r = S + 2 * (f - 1) + rowsub;
            if (f >= 1 && r >= x1lo && r <= x1hi) {
                int b = s_base[r + 2];
                if (b < 128) {
                    int sl0 = (r + 4) % 5, sl1 = r % 5, sl2 = (r + 1) % 5;
                    int db0 = b - s_base[r + 1] - 1;
                    int db2 = b - s_base[r + 3] - 1;
                    float vin[9];
                    {
                        const float* r0 = &s_in[sl0][0];
                        const float* r1 = &s_in[sl1][0];
                        const float* r2 = &s_in[sl2][0];
                        int i0 = col + db0, i1 = col - 1, i2 = col + db2;
                        vin[0] = lds_self(r0, i0, zp); vin[1] = lds_self(r0, i0 + 1, zp); vin[2] = lds_self(r0, i0 + 2, zp);
                        vin[3] = lds_self(r1, i1, zp); vin[4] = lds_self(r1, i1 + 1, zp); vin[5] = lds_self(r1, i1 + 2, zp);
                        vin[6] = lds_self(r2, i2, zp); vin[7] = lds_self(r2, i2 + 1, zp); vin[8] = lds_self(r2, i2 + 2, zp);
                    }
                    s16x8 pk;
#pragma unroll
                    for (int o = 0; o < 8; ++o) {
                        int oc = grp * 8 + o;
                        const float* wp = w1 + oc * 9;
                        float a = b1[oc];
#pragma unroll
                        for (int j = 0; j < 9; ++j) a = fmaf(wp[j], vin[j], a);
                        pk[o] = f2bf(fmaxf(a, 0.f));
                    }
                    *(s16x8*)&s_x1[sl1][col * 40 + grp * 8] = pk;
                }
            }

            const int rp3c = S + 2 * (f - 3);
            const bool act3c = (f >= 3) && (rp3c <= x2hi) && (rp3c + 1 >= x2lo);
            if (act3c) {
                int rv = grp & 1, nt = grp >> 1;
                int rA = rp3c + rv;
                const short* bp = &s_x2[rv][(nt * 16 + n) * 72 + (quad << 3)];
                s16x8 bf0 = *(const s16x8*)bp;
                s16x8 bf1 = *(const s16x8*)(bp + 32);
                fx4 a3 = {0.f, 0.f, 0.f, 0.f};
                a3 = __builtin_amdgcn_mfma_f32_16x16x32_bf16(w3f0, bf0, a3, 0, 0, 0);
                a3 = __builtin_amdgcn_mfma_f32_16x16x32_bf16(w3f1, bf1, a3, 0, 0, 0);
                int dslot = rA % 5;
#pragma unroll
                for (int e = 0; e < 4; ++e) {
                    int m = (quad << 2) + e;
                    if (m < 9) s_D[dslot][m][nt * 16 + n] = a3[e];
                }
            }
        }
        __syncthreads();

        // ================= Seg C: CONV2 (pair f-2) =================
        {
            const int rp = S + 2 * (f - 2);
            const bool act2 = (f >= 2) && (rp <= x2hi) && (rp + 1 >= x2lo);
            if (act2) {
                int bm1 = s_base[rp + 1];
                int b0  = s_base[rp + 2];
                int b1v = s_base[rp + 3];
                int b2v = s_base[rp + 4];
                bool v0 = (rp >= x2lo) && (rp <= x2hi) && (b0 < 128);
                bool v1 = (rp + 1 >= x2lo) && (rp + 1 <= x2hi) && (b1v < 128);
                int db[2][3];
                db[0][0] = v0 ? (b0 - bm1 - 1) : SENT;
                db[0][1] = v0 ? (-1)           : SENT;
                db[0][2] = v0 ? (b0 - b1v - 1) : SENT;
                db[1][0] = v1 ? (b1v - b0 - 1) : SENT;
                db[1][1] = v1 ? (-1)           : SENT;
                db[1][2] = v1 ? (b1v - b2v - 1): SENT;
                int slot[4];
                slot[0] = (rp + 4) % 5;
                slot[1] = rp % 5;
                slot[2] = (rp + 1) % 5;
                slot[3] = (rp + 2) % 5;

                fx4 acc[4];
#pragma unroll
                for (int t = 0; t < 4; ++t) acc[t] = binit;

#pragma unroll
                for (int ks = 0; ks < 9; ++ks) {
                    const int dy = ks / 3, dxp = ks % 3;
#pragma unroll
                    for (int t = 0; t < 4; ++t) {
                        int rv = t >> 1;
                        int idx = ((t & 1) << 4) + n + dxp + db[rv][dy];
                        const short* bp = ((unsigned)idx < 32u)
                            ? &s_x1[slot[rv + dy]][idx * 40 + (quad << 3)]
                            : z16;
                        s16x8 bfrag = *(const s16x8*)bp;
                        acc[t] = __builtin_amdgcn_mfma_f32_16x16x32_bf16(
                                     afrag2[ks], bfrag, acc[t], 0, 0, 0);
                    }
                }
#pragma unroll
                for (int t = 0; t < 4; ++t) {
                    int rv = t >> 1;
                    int colw = ((t & 1) << 4) + n;
                    s16x4 pk;
#pragma unroll
                    for (int e = 0; e < 4; ++e)
                        pk[e] = f2bf(fmaxf(acc[t][e], 0.f));
                    *(s16x4*)&s_x2[rv][colw * 72 + (grp << 4) + (quad << 2)] = pk;
                }
            }
        }
        __syncthreads();

        // ================= Seg D: COMBINE (pair f-4) =================
        {
            const int rp4 = S + 2 * (f - 4);
            const bool act4 = (f >= 4) && (rp4 <= ohi) && (rp4 + 1 >= olo);
            if (act4 && tid < 64) {
                int rs = tid >> 5, c = tid & 31;
                int r = rp4 + rs;
                if (r >= olo && r <= ohi) {
                    int b = s_base[r + 2];
                    float o = 0.f;
                    if (b < 128) {
#pragma unroll
                        for (int dy = 0; dy < 3; ++dy) {
                            int rq = r - 1 + dy;
                            int bb = s_base[rq + 2];
                            int idx0 = c - 1 + b - bb;
                            int ds = ((rq % 5) + 5) % 5;
                            const float* Dp = &s_D[ds][dy * 3][0];
#pragma unroll
                            for (int dxp = 0; dxp < 3; ++dxp) {
                                int idx = idx0 + dxp;
                                if ((unsigned)idx < 32u) o += Dp[dxp * 34 + idx];
                            }
                        }
                    }
                    s_out3[f & 1][rs][c] = o + b3s;
                }
            }
        }
        __syncthreads();
    }

    if (tid < 200) s_lin[tid] = lacc;
    __syncthreads();
    if (tid < 25) {
        float s = 0.f;
#pragma unroll
        for (int g = 0; g < 8; ++g) s += s_lin[tid * 8 + g];
        patches[pb * 25 + tid] = s;
    }
}

// ---------------------------------------------------------------------------
// Merged finish + radon (R6-verified): 60 blocks x 1024 thr; y_hat built in
// LDS; block 0 writes y_hat; radon samples from LDS.
// ---------------------------------------------------------------------------
__device__ __forceinline__ float rad_sample(const float* img, int xi, int yi)
{
    bool valid = (xi >= 0) & (xi < 128) & (yi >= 0) & (yi < 128);
    int xc = xi < 0 ? 0 : (xi > 127 ? 127 : xi);
    int yc = yi < 0 ? 0 : (yi > 127 ? 127 : yi);
    float v = img[yc * 128 + xc];
    return valid ? v : 0.f;
}

__global__ __launch_bounds__(1024) void k_finrad(const float* __restrict__ patches,
                                                 const float* __restrict__ linb,
                                                 float* __restrict__ out)
{
    __shared__ float img[128 * 128];
    __shared__ float s_r[8][128];
    const int tid = threadIdx.x;
    const int a = blockIdx.x;

#pragma unroll
    for (int j = 0; j < 16; ++j) {
        int i = j * 1024 + tid;
        int y = i >> 7, x = i & 127;
        float rec = 0.f;
        if (y < 125 && x < 125) {
            int pp = (y / 5) * 25 + (x / 5);
            int k  = (y % 5) * 5 + (x % 5);
            rec = patches[(2 * pp) * 25 + k] + patches[(2 * pp + 1) * 25 + k]
                + linb[k];
        }
        float sig = 1.f / (1.f + expf(-rec));
        img[i] = sig;
        if (a == 0) out[i] = sig;
    }
    __syncthreads();

    int t = tid & 127, sub = tid >> 7;
    double ang = (double)a * (M_PI / 180.0);
    float ct = (float)cos(ang);
    float st = (float)sin(ang);
    const float c = 63.5f;
    float tt = (float)t - c;
    float sum = 0.f;
    for (int s = sub * 16; s < sub * 16 + 16; ++s) {
        float ss = (float)s - c;
        float x = c + tt * ct - ss * st;
        float y = c + tt * st + ss * ct;
        float fx = floorf(x), fy = floorf(y);
        int x0 = (int)fx, y0 = (int)fy;
        float wx = x - fx, wy = y - fy;
        float v00 = rad_sample(img, x0,     y0);
        float v10 = rad_sample(img, x0 + 1, y0);
        float v01 = rad_sample(img, x0,     y0 + 1);
        float v11 = rad_sample(img, x0 + 1, y0 + 1);
        sum += v00 * (1.f - wx) * (1.f - wy)
             + v10 * wx * (1.f - wy)
             + v01 * (1.f - wx) * wy
             + v11 * wx * wy;
    }
    s_r[sub][t] = sum;
    __syncthreads();
    if (sub == 0) {
        float tot = 0.f;
#pragma unroll
        for (int k = 0; k < 8; ++k) tot += s_r[k][t];
        out[128 * 128 + a * 128 + t] = tot;
    }
}

// ---------------------------------------------------------------------------
extern "C" void kernel_launch(void* const* d_in, const int* in_sizes, int n_in,
                              void* d_out, int out_size, void* d_ws, size_t ws_size,
                              hipStream_t stream)
{
    (void)in_sizes; (void)n_in; (void)out_size; (void)ws_size;

    const float* sino  = (const float*)d_in[0];
    const float* w1    = (const float*)d_in[1];
    const float* b1    = (const float*)d_in[2];
    const float* w2    = (const float*)d_in[3];
    const float* b2    = (const float*)d_in[4];
    const float* w3    = (const float*)d_in[5];
    const float* b3    = (const float*)d_in[6];
    const float* lw    = (const float*)d_in[7];
    const float* lb    = (const float*)d_in[8];
    const int*   masks = (const int*)d_in[9];

    float* out = (float*)d_out;

    char* ws = (char*)d_ws;
    float* patches = (float*)ws;                        // 1250*25 fl = 125 KB
    int*   win     = (int*)(ws + 128 * 1024);           // 160 KB
    short* w2a     = (short*)(ws + 288 * 1024);         // 36 KB
    short* w3a     = (short*)(ws + 328 * 1024);         // 2 KB

    k_prep<<<698, 256, 0, stream>>>(masks, w2, w3, win, w2a, w3a);
    k_pipeline<<<2 * NPATCH, 256, 0, stream>>>(sino, w1, b1, w2a, b2, w3a, b3,
                                               lw, masks, win, patches);
    k_finrad<<<A_DIM, 1024, 0, stream>>>(patches, lb, out);
}

// Round 8
// 217.458 us; speedup vs baseline: 1.4108x; 1.4108x over previous
//
#include <hip/hip_runtime.h>
#include <math.h>

#define A_DIM 60
#define NPATCH 625
#define SENT (1 << 20)

typedef short s16x8 __attribute__((ext_vector_type(8)));
typedef short s16x4 __attribute__((ext_vector_type(4)));
typedef float fx4   __attribute__((ext_vector_type(4)));

__device__ __forceinline__ short f2bf(float f) {
    unsigned u = __builtin_bit_cast(unsigned, f);
    unsigned r = (u + 0x7FFFu + ((u >> 16) & 1u)) >> 16;
    return (short)r;
}

// ---------------------------------------------------------------------------
// Prep (merged, cheap): blocks 0..624 -> window bases; 625..696 -> w2 A-pack;
// 697 -> w3 A-pack. (R5-verified)
// ---------------------------------------------------------------------------
__global__ __launch_bounds__(256) void k_prep(const int* __restrict__ masks,
                                              const float* __restrict__ w2,
                                              const float* __restrict__ w3,
                                              int* __restrict__ win,
                                              short* __restrict__ w2a,
                                              short* __restrict__ w3a)
{
    const int blk = blockIdx.x, tid = threadIdx.x;
    if (blk < NPATCH) {
        __shared__ int s_f[60][4];
        __shared__ int s_row[64];
        int r = tid >> 2, q = tid & 3;
        if (r < 60) {
            const int4* m4 = (const int4*)(masks + (blk * 60 + r) * 128 + q * 32);
            int first = SENT;
#pragma unroll
            for (int j = 0; j < 8; ++j) {
                int4 v = m4[j];
                int base = q * 32 + j * 4;
                if (v.w) first = min(first, base + 3);
                if (v.z) first = min(first, base + 2);
                if (v.y) first = min(first, base + 1);
                if (v.x) first = min(first, base);
            }
            s_f[r][q] = first;
        }
        __syncthreads();
        if (tid < 60)
            s_row[tid] = min(min(s_f[tid][0], s_f[tid][1]),
                             min(s_f[tid][2], s_f[tid][3]));
        __syncthreads();
        if (tid < 60) {
            int lo = SENT;
            for (int d = -3; d <= 3; ++d) {
                int rr = tid + d;
                if (rr >= 0 && rr < 60) lo = min(lo, s_row[rr]);
            }
            int b;
            if (lo >= SENT) b = SENT;
            else { b = lo - 3; if (b < 0) b = 0; if (b > 96) b = 96; }
            win[blk * 64 + tid] = b;
        }
    } else if (blk < 697) {
        int i = (blk - NPATCH) * 256 + tid;     // < 18432
        int ic = i & 31, ol = (i >> 5) & 15, b2i = i >> 9;
        int ks = b2i % 9, T = b2i / 9;
        int oc = T * 16 + ol, dy = ks / 3, dxx = ks % 3;
        w2a[i] = f2bf(w2[((oc * 32 + ic) * 3 + dy) * 3 + dxx]);
    } else {
#pragma unroll
        for (int jj = 0; jj < 4; ++jj) {
            int i = jj * 256 + tid;             // < 1024
            int k = i & 31, m = (i >> 5) & 15, s = i >> 9;
            int dy = m / 3, dxx = m % 3;
            float v = (m < 9) ? w3[((s * 32 + k) * 3 + dy) * 3 + dxx] : 0.f;
            w3a[i] = f2bf(v);
        }
    }
}

// ---------------------------------------------------------------------------
// Main pipeline: 2 blocks/patch, pair of rows per iter, 4 barriers/iter.
// Single s_x2 pair buffer -> 30.7 KB LDS -> 5 blocks/CU by LDS alone.
// __launch_bounds__(256,4): do NOT force 5 waves/EU — that caps VGPR at ~100
// and spills the 36-VGPR afrag2 array to scratch (R7: 127MB scratch writes,
// 211us). At 4 the compiler uses ~64 VGPR, no spills, LDS still gives 5/CU.
// Seg A: s_in write (prefetched) + next prefetch + LINEAR(f-5) + linw prefetch
// Seg B: CONV1 (pair f-1) + conv3 tap-GEMM (pair f-3, s_x2 from prev Seg C)
// Seg C: CONV2 MFMA (pair f-2) -> s_x2
// Seg D: COMBINE (pair f-4) -> s_out3[f&1]
// ---------------------------------------------------------------------------
__device__ __forceinline__ float lds_self(const float* rowp, int idx,
                                          const float* zp)
{
    const float* q = ((unsigned)idx < 32u) ? (rowp + idx) : zp;
    return *q;
}

__global__ __launch_bounds__(256, 4) void k_pipeline(
    const float* __restrict__ sino,
    const float* __restrict__ w1, const float* __restrict__ b1,
    const short* __restrict__ w2a, const float* __restrict__ b2w,
    const short* __restrict__ w3a, const float* __restrict__ b3,
    const float* __restrict__ linw,
    const int* __restrict__ masks, const int* __restrict__ win,
    float* __restrict__ patches)
{
    __shared__ float s_in[5][33];
    __shared__ __align__(16) short s_x1[5][32 * 40];   // ring 5: [col][32ic+pad]
    __shared__ __align__(16) short s_x2[2][32 * 72];   // single pair buffer
    __shared__ float s_D[5][9][34];                    // conv3 tap ring
    __shared__ float s_out3[2][2][32];                 // dbl-buffer pairs
    __shared__ float s_lin[200];
    __shared__ int   s_base[64];
    __shared__ __align__(16) short s_z32[16];          // 32B zeros

    const int tid = threadIdx.x;
    const int pb  = blockIdx.x;
    const int p   = pb >> 1;
    const int half = pb & 1;

    const int S     = half ? 27 : 0;
    const int in_hi = half ? 59 : 32;
    const int x1lo  = half ? 28 : 0,  x1hi = half ? 59 : 31;
    const int x2lo  = half ? 29 : 0,  x2hi = half ? 59 : 30;
    const int olo   = half ? 30 : 0,  ohi  = half ? 59 : 29;
    const int F     = half ? 22 : 20;

    // early-exit for fully-empty patches (also first barrier)
    int pred = (tid < 60) ? ((win[p * 64 + tid] < 128) ? 1 : 0) : 0;
    if (__syncthreads_count(pred) == 0) {
        if (tid < 25) patches[pb * 25 + tid] = 0.f;
        return;
    }

    if (tid < 64)
        s_base[tid] = (tid >= 2 && tid < 62) ? win[p * 64 + (tid - 2)] : SENT;
    if (tid < 16) s_z32[tid] = 0;

    const int lane   = tid & 63;
    const int n      = lane & 15;
    const int quad   = lane >> 4;
    const int col    = tid & 31;
    const int rowsub = (tid >> 5) & 1;
    const int grp    = __builtin_amdgcn_readfirstlane(tid >> 6);  // 0..3
    const float* zp  = (const float*)&s_z32[0];
    const short* z16 = &s_z32[0];

    // hoisted invariants
    s16x8 afrag2[9];
#pragma unroll
    for (int ks = 0; ks < 9; ++ks)
        afrag2[ks] = *(const s16x8*)(w2a + (grp * 9 + ks) * 512 + (n << 5) + (quad << 3));
    const s16x8 w3f0 = *(const s16x8*)(w3a + (n << 5) + (quad << 3));
    const s16x8 w3f1 = *(const s16x8*)(w3a + ((16 + n) << 5) + (quad << 3));
    const float4 bv = *(const float4*)(b2w + (grp << 4) + (quad << 2));
    fx4 binit; binit[0] = bv.x; binit[1] = bv.y; binit[2] = bv.z; binit[3] = bv.w;
    const float b3s = b3[0];

    const int lk = tid >> 3;
    const int lg = tid & 7;
    float lacc = 0.f;
    float pwv[2][4] = {{0.f,0.f,0.f,0.f},{0.f,0.f,0.f,0.f}};
    float pv = 0.f; int pm = 0;

    __syncthreads();

    // pre-loop input prefetch (pair 0)
    if (tid < 64) {
        int r = S + (tid >> 5);
        int b = s_base[r + 2];
        if (r <= in_hi && b < 128) {
            int t = b + col;
            pm = masks[(p * A_DIM + r) * 128 + t];
            pv = sino[r * 128 + t];
        }
    }

    for (int f = 0; f < F; ++f) {
        // ================= Seg A =================
        if (tid < 64) {
            int r = S + 2 * f + (tid >> 5);
            int b = s_base[r + 2];
            if (r <= in_hi && b < 128)
                s_in[r % 5][col] = pm ? pv : 0.f;
            int r2 = r + 2;                       // prefetch pair f+1
            int b2i = s_base[r2 + 2];
            if (r2 <= in_hi && b2i < 128) {
                int t = b2i + col;
                pm = masks[(p * A_DIM + r2) * 128 + t];
                pv = sino[r2 * 128 + t];
            }
        }
        {
            int q = f - 5;                        // LINEAR on pair f-5
            if (q >= 0 && tid < 200) {
#pragma unroll
                for (int rs = 0; rs < 2; ++rs) {
                    int r = S + 2 * q + rs;
                    if (r >= olo && r <= ohi) {
                        int b = s_base[r + 2];
                        if (b < 128) {
                            float a = lacc;
#pragma unroll
                            for (int i = 0; i < 4; ++i)
                                a = fmaf(s_out3[(f + 1) & 1][rs][lg + 8 * i],
                                         pwv[rs][i], a);
                            lacc = a;
                        }
                    }
                }
            }
            int q2 = f - 4;                       // linw prefetch for pair f-4
            if (q2 >= 0 && tid < 200) {
#pragma unroll
                for (int rs = 0; rs < 2; ++rs) {
                    int r = S + 2 * q2 + rs;
                    if (r >= olo && r <= ohi) {
                        int b = s_base[r + 2];
                        if (b < 128) {
                            const float* lwp = linw + lk * (A_DIM * 128) + r * 128 + b;
#pragma unroll
                            for (int i = 0; i < 4; ++i)
                                pwv[rs][i] = lwp[lg + 8 * i];
                        }
                    }
                }
            }
        }
        __syncthreads();

        // ========= Seg B: CONV1 (pair f-1) + conv3 tap (pair f-3) =========
        {
            int r = S + 2 * (f - 1) + rowsub;
            if (f >= 1 && r >= x1lo && r <= x1hi) {
                int b = s_base[r + 2];
                if (b < 128) {
                    int sl0 = (r + 4) % 5, sl1 = r % 5, sl2 = (r + 1) % 5;
                    int db0 = b - s_base[r + 1] - 1;
                    int db2 = b - s_base[r + 3] - 1;
                    float vin[9];
                    {
                        const float* r0 = &s_in[sl0][0];
                        const float* r1 = &s_in[sl1][0];
                        const float* r2 = &s_in[sl2][0];
                        int i0 = col + db0, i1 = col - 1, i2 = col + db2;
                        vin[0] = lds_self(r0, i0, zp); vin[1] = lds_self(r0, i0 + 1, zp); vin[2] = lds_self(r0, i0 + 2, zp);
                        vin[3] = lds_self(r1, i1, zp); vin[4] = lds_self(r1, i1 + 1, zp); vin[5] = lds_self(r1, i1 + 2, zp);
                        vin[6] = lds_self(r2, i2, zp); vin[7] = lds_self(r2, i2 + 1, zp); vin[8] = lds_self(r2, i2 + 2, zp);
                    }
                    s16x8 pk;
#pragma unroll
                    for (int o = 0; o < 8; ++o) {
                        int oc = grp * 8 + o;
                        const float* wp = w1 + oc * 9;
                        float a = b1[oc];
#pragma unroll
                        for (int j = 0; j < 9; ++j) a = fmaf(wp[j], vin[j], a);
                        pk[o] = f2bf(fmaxf(a, 0.f));
                    }
                    *(s16x8*)&s_x1[sl1][col * 40 + grp * 8] = pk;
                }
            }

            const int rp3c = S + 2 * (f - 3);
            const bool act3c = (f >= 3) && (rp3c <= x2hi) && (rp3c + 1 >= x2lo);
            if (act3c) {
                int rv = grp & 1, nt = grp >> 1;
                int rA = rp3c + rv;
                const short* bp = &s_x2[rv][(nt * 16 + n) * 72 + (quad << 3)];
                s16x8 bf0 = *(const s16x8*)bp;
                s16x8 bf1 = *(const s16x8*)(bp + 32);
                fx4 a3 = {0.f, 0.f, 0.f, 0.f};
                a3 = __builtin_amdgcn_mfma_f32_16x16x32_bf16(w3f0, bf0, a3, 0, 0, 0);
                a3 = __builtin_amdgcn_mfma_f32_16x16x32_bf16(w3f1, bf1, a3, 0, 0, 0);
                int dslot = rA % 5;
#pragma unroll
                for (int e = 0; e < 4; ++e) {
                    int m = (quad << 2) + e;
                    if (m < 9) s_D[dslot][m][nt * 16 + n] = a3[e];
                }
            }
        }
        __syncthreads();

        // ================= Seg C: CONV2 (pair f-2) =================
        {
            const int rp = S + 2 * (f - 2);
            const bool act2 = (f >= 2) && (rp <= x2hi) && (rp + 1 >= x2lo);
            if (act2) {
                int bm1 = s_base[rp + 1];
                int b0  = s_base[rp + 2];
                int b1v = s_base[rp + 3];
                int b2v = s_base[rp + 4];
                bool v0 = (rp >= x2lo) && (rp <= x2hi) && (b0 < 128);
                bool v1 = (rp + 1 >= x2lo) && (rp + 1 <= x2hi) && (b1v < 128);
                int db[2][3];
                db[0][0] = v0 ? (b0 - bm1 - 1) : SENT;
                db[0][1] = v0 ? (-1)           : SENT;
                db[0][2] = v0 ? (b0 - b1v - 1) : SENT;
                db[1][0] = v1 ? (b1v - b0 - 1) : SENT;
                db[1][1] = v1 ? (-1)           : SENT;
                db[1][2] = v1 ? (b1v - b2v - 1): SENT;
                int slot[4];
                slot[0] = (rp + 4) % 5;
                slot[1] = rp % 5;
                slot[2] = (rp + 1) % 5;
                slot[3] = (rp + 2) % 5;

                fx4 acc[4];
#pragma unroll
                for (int t = 0; t < 4; ++t) acc[t] = binit;

#pragma unroll
                for (int ks = 0; ks < 9; ++ks) {
                    const int dy = ks / 3, dxp = ks % 3;
#pragma unroll
                    for (int t = 0; t < 4; ++t) {
                        int rv = t >> 1;
                        int idx = ((t & 1) << 4) + n + dxp + db[rv][dy];
                        const short* bp = ((unsigned)idx < 32u)
                            ? &s_x1[slot[rv + dy]][idx * 40 + (quad << 3)]
                            : z16;
                        s16x8 bfrag = *(const s16x8*)bp;
                        acc[t] = __builtin_amdgcn_mfma_f32_16x16x32_bf16(
                                     afrag2[ks], bfrag, acc[t], 0, 0, 0);
                    }
                }
#pragma unroll
                for (int t = 0; t < 4; ++t) {
                    int rv = t >> 1;
                    int colw = ((t & 1) << 4) + n;
                    s16x4 pk;
#pragma unroll
                    for (int e = 0; e < 4; ++e)
                        pk[e] = f2bf(fmaxf(acc[t][e], 0.f));
                    *(s16x4*)&s_x2[rv][colw * 72 + (grp << 4) + (quad << 2)] = pk;
                }
            }
        }
        __syncthreads();

        // ================= Seg D: COMBINE (pair f-4) =================
        {
            const int rp4 = S + 2 * (f - 4);
            const bool act4 = (f >= 4) && (rp4 <= ohi) && (rp4 + 1 >= olo);
            if (act4 && tid < 64) {
                int rs = tid >> 5, c = tid & 31;
                int r = rp4 + rs;
                if (r >= olo && r <= ohi) {
                    int b = s_base[r + 2];
                    float o = 0.f;
                    if (b < 128) {
#pragma unroll
                        for (int dy = 0; dy < 3; ++dy) {
                            int rq = r - 1 + dy;
                            int bb = s_base[rq + 2];
                            int idx0 = c - 1 + b - bb;
                            int ds = ((rq % 5) + 5) % 5;
                            const float* Dp = &s_D[ds][dy * 3][0];
#pragma unroll
                            for (int dxp = 0; dxp < 3; ++dxp) {
                                int idx = idx0 + dxp;
                                if ((unsigned)idx < 32u) o += Dp[dxp * 34 + idx];
                            }
                        }
                    }
                    s_out3[f & 1][rs][c] = o + b3s;
                }
            }
        }
        __syncthreads();
    }

    if (tid < 200) s_lin[tid] = lacc;
    __syncthreads();
    if (tid < 25) {
        float s = 0.f;
#pragma unroll
        for (int g = 0; g < 8; ++g) s += s_lin[tid * 8 + g];
        patches[pb * 25 + tid] = s;
    }
}

// ---------------------------------------------------------------------------
// Merged finish + radon (R6-verified): 60 blocks x 1024 thr; y_hat built in
// LDS; block 0 writes y_hat; radon samples from LDS.
// ---------------------------------------------------------------------------
__device__ __forceinline__ float rad_sample(const float* img, int xi, int yi)
{
    bool valid = (xi >= 0) & (xi < 128) & (yi >= 0) & (yi < 128);
    int xc = xi < 0 ? 0 : (xi > 127 ? 127 : xi);
    int yc = yi < 0 ? 0 : (yi > 127 ? 127 : yi);
    float v = img[yc * 128 + xc];
    return valid ? v : 0.f;
}

__global__ __launch_bounds__(1024) void k_finrad(const float* __restrict__ patches,
                                                 const float* __restrict__ linb,
                                                 float* __restrict__ out)
{
    __shared__ float img[128 * 128];
    __shared__ float s_r[8][128];
    const int tid = threadIdx.x;
    const int a = blockIdx.x;

#pragma unroll
    for (int j = 0; j < 16; ++j) {
        int i = j * 1024 + tid;
        int y = i >> 7, x = i & 127;
        float rec = 0.f;
        if (y < 125 && x < 125) {
            int pp = (y / 5) * 25 + (x / 5);
            int k  = (y % 5) * 5 + (x % 5);
            rec = patches[(2 * pp) * 25 + k] + patches[(2 * pp + 1) * 25 + k]
                + linb[k];
        }
        float sig = 1.f / (1.f + expf(-rec));
        img[i] = sig;
        if (a == 0) out[i] = sig;
    }
    __syncthreads();

    int t = tid & 127, sub = tid >> 7;
    double ang = (double)a * (M_PI / 180.0);
    float ct = (float)cos(ang);
    float st = (float)sin(ang);
    const float c = 63.5f;
    float tt = (float)t - c;
    float sum = 0.f;
    for (int s = sub * 16; s < sub * 16 + 16; ++s) {
        float ss = (float)s - c;
        float x = c + tt * ct - ss * st;
        float y = c + tt * st + ss * ct;
        float fx = floorf(x), fy = floorf(y);
        int x0 = (int)fx, y0 = (int)fy;
        float wx = x - fx, wy = y - fy;
        float v00 = rad_sample(img, x0,     y0);
        float v10 = rad_sample(img, x0 + 1, y0);
        float v01 = rad_sample(img, x0,     y0 + 1);
        float v11 = rad_sample(img, x0 + 1, y0 + 1);
        sum += v00 * (1.f - wx) * (1.f - wy)
             + v10 * wx * (1.f - wy)
             + v01 * (1.f - wx) * wy
             + v11 * wx * wy;
    }
    s_r[sub][t] = sum;
    __syncthreads();
    if (sub == 0) {
        float tot = 0.f;
#pragma unroll
        for (int k = 0; k < 8; ++k) tot += s_r[k][t];
        out[128 * 128 + a * 128 + t] = tot;
    }
}

// ---------------------------------------------------------------------------
extern "C" void kernel_launch(void* const* d_in, const int* in_sizes, int n_in,
                              void* d_out, int out_size, void* d_ws, size_t ws_size,
                              hipStream_t stream)
{
    (void)in_sizes; (void)n_in; (void)out_size; (void)ws_size;

    const float* sino  = (const float*)d_in[0];
    const float* w1    = (const float*)d_in[1];
    const float* b1    = (const float*)d_in[2];
    const float* w2    = (const float*)d_in[3];
    const float* b2    = (const float*)d_in[4];
    const float* w3    = (const float*)d_in[5];
    const float* b3    = (const float*)d_in[6];
    const float* lw    = (const float*)d_in[7];
    const float* lb    = (const float*)d_in[8];
    const int*   masks = (const int*)d_in[9];

    float* out = (float*)d_out;

    char* ws = (char*)d_ws;
    float* patches = (float*)ws;                        // 1250*25 fl = 125 KB
    int*   win     = (int*)(ws + 128 * 1024);           // 160 KB
    short* w2a     = (short*)(ws + 288 * 1024);         // 36 KB
    short* w3a     = (short*)(ws + 328 * 1024);         // 2 KB

    k_prep<<<698, 256, 0, stream>>>(masks, w2, w3, win, w2a, w3a);
    k_pipeline<<<2 * NPATCH, 256, 0, stream>>>(sino, w1, b1, w2a, b2, w3a, b3,
                                               lw, masks, win, patches);
    k_finrad<<<A_DIM, 1024, 0, stream>>>(patches, lb, out);
}